// Round 4
// baseline (435.797 us; speedup 1.0000x reference)
//
#include <hip/hip_runtime.h>

// out[b,c,h,w] = x[b,c,h+1,w] - x[b,c,h,w]
// x: (16, 64, 512, 512) fp32, out: (16, 64, 511, 512) fp32
//
// Persistent grid-stride streaming kernel: 2048 blocks x 256 threads (= one
// full residency at 8 blocks/CU, no block re-dispatch). Flat sweep over the
// output index space keeps the whole grid's memory frontier contiguous
// (copy-kernel pattern); row-boundary re-reads are absorbed by L2/L3.

typedef float f32x4 __attribute__((ext_vector_type(4)));

#define W4        128                      // 512 floats / 4 per row
#define PLANE_OUT (511 * W4)               // 65408 float4 per out plane
#define TOTAL_OUT (1024u * PLANE_OUT)      // 66,977,792 float4
#define NBLOCKS   2048

__global__ __launch_bounds__(256) void PartialDerivative_kernel(
    const f32x4* __restrict__ x, f32x4* __restrict__ out) {
    const unsigned stride = NBLOCKS * 256;
    for (unsigned idx = blockIdx.x * 256 + threadIdx.x; idx < TOTAL_OUT;
         idx += stride) {
        const unsigned plane = idx / PLANE_OUT;          // magic-mul div
        const size_t in_idx = (size_t)idx + (size_t)plane * W4;  // plane stride 65536
        f32x4 a = x[in_idx];
        f32x4 b = x[in_idx + W4];
        out[idx] = b - a;
    }
}

extern "C" void kernel_launch(void* const* d_in, const int* in_sizes, int n_in,
                              void* d_out, int out_size, void* d_ws, size_t ws_size,
                              hipStream_t stream) {
    const f32x4* x = (const f32x4*)d_in[0];
    f32x4* out = (f32x4*)d_out;
    PartialDerivative_kernel<<<dim3(NBLOCKS), dim3(256), 0, stream>>>(x, out);
}

// Round 5
// 375.199 us; speedup vs baseline: 1.1615x; 1.1615x over previous
//
#include <hip/hip_runtime.h>

// out[b,c,h,w] = x[b,c,h+1,w] - x[b,c,h,w]
// x: (16, 64, 512, 512) fp32, out: (16, 64, 511, 512) fp32
//
// Round-1 structure (one float4 output per thread, flat sweep) + chunked
// XCD-aware block swizzle: each of the 8 XCDs gets a contiguous 32768-block
// (= 128-plane) range, so vertically-adjacent blocks (which share a boundary
// input row) run on the SAME XCD and the re-read hits that XCD's L2 instead
// of going back to L3/HBM.

typedef float f32x4 __attribute__((ext_vector_type(4)));

#define W4        128                  // 512 floats / 4 per row
#define H_IN      512
#define H_OUT     511
#define PLANE_OUT (H_OUT * W4)         // 65408
#define PLANE_IN  (H_IN * W4)          // 65536
#define NWG       (1024 * 256)         // 262144 blocks (256 per plane)
#define NXCD      8
#define CPX       (NWG / NXCD)         // 32768 blocks per XCD chunk

__global__ __launch_bounds__(256) void PartialDerivative_kernel(
    const f32x4* __restrict__ x, f32x4* __restrict__ out) {
    // bijective chunked XCD swizzle (NWG % 8 == 0)
    const unsigned wgid = blockIdx.x;
    const unsigned swz  = (wgid & (NXCD - 1)) * CPX + (wgid >> 3);

    const unsigned plane = swz >> 8;            // 256 blocks per plane
    const unsigned tid   = ((swz & 255u) << 8) | threadIdx.x;  // 0..65535
    if (tid >= PLANE_OUT) return;

    const size_t in_idx = (size_t)plane * PLANE_IN + tid;
    f32x4 a = x[in_idx];
    f32x4 b = x[in_idx + W4];
    out[(size_t)plane * PLANE_OUT + tid] = b - a;
}

extern "C" void kernel_launch(void* const* d_in, const int* in_sizes, int n_in,
                              void* d_out, int out_size, void* d_ws, size_t ws_size,
                              hipStream_t stream) {
    const f32x4* x = (const f32x4*)d_in[0];
    f32x4* out = (f32x4*)d_out;
    PartialDerivative_kernel<<<dim3(NWG), dim3(256), 0, stream>>>(x, out);
}